// Round 11
// baseline (271.991 us; speedup 1.0000x reference)
//
#include <hip/hip_runtime.h>
#include <hip/hip_bf16.h>

#define VOCAB 2048
#define EMBD  256
#define LATD  64
#define TLEN  32
#define BATCH 64
#define NBLK  256
#define NCG   128   // column groups (16 vocab cols each); rows split 2-way

typedef __attribute__((ext_vector_type(8))) short bf16x8;
typedef __attribute__((ext_vector_type(4))) float f32x4;

// barrier buffer layout (words):
//   halfArr[256]  : rg*128 + cg
//   halfRel[256]  : line (rg*8 + xg), 16-word stride
//   fullArr[256]  : physical j
//   fullRel[128]  : line (j&7), 16-word stride
#define BAR_WORDS 896

// ---------------- init: h ring slot0 = 0, barrier = 0 ----------------
__global__ void k_init(ushort* __restrict__ h0, unsigned* __restrict__ bar) {
  int i = blockIdx.x * 256 + threadIdx.x;   // grid 512*256 = 131072
  h0[i] = 0;                                 // 64*2048 bf16 (ring slot 0)
  if (i < BAR_WORDS) bar[i] = 0;
}

// ---------- transpose+convert: src[K][8192] f32 -> dst[8192][K] bf16 ----------
__global__ void k_transpose(const float* __restrict__ src,
                            __hip_bfloat16* __restrict__ dst, int K) {
  __shared__ __hip_bfloat16 tile[64][72];
  int k0 = (blockIdx.x >> 7) * 64;
  int n0 = (blockIdx.x & 127) * 64;
  int tid = threadIdx.x;
  {
    int kl = tid >> 2;
    int nq = (tid & 3) << 4;
    const float* s = src + (size_t)(k0 + kl) * 8192 + n0 + nq;
#pragma unroll
    for (int i = 0; i < 4; ++i) {
      float4 v = *reinterpret_cast<const float4*>(s + i * 4);
      tile[nq + i * 4 + 0][kl] = __float2bfloat16(v.x);
      tile[nq + i * 4 + 1][kl] = __float2bfloat16(v.y);
      tile[nq + i * 4 + 2][kl] = __float2bfloat16(v.z);
      tile[nq + i * 4 + 3][kl] = __float2bfloat16(v.w);
    }
  }
  __syncthreads();
  {
    int nl = tid >> 2;
    int kq = (tid & 3) << 4;
    uint4* d = reinterpret_cast<uint4*>(dst + (size_t)(n0 + nl) * K + k0 + kq);
    const uint4* s = reinterpret_cast<const uint4*>(&tile[nl][kq]);
    d[0] = s[0];
    d[1] = s[1];
  }
}

// ---------- gather: xb[t*64+b][256] = bf16(emb[tokens[b][t]]) ----------
__global__ void k_gather(const int* __restrict__ tokens,
                         const float* __restrict__ emb,
                         __hip_bfloat16* __restrict__ xb) {
  int tid = threadIdx.x;
  int row = blockIdx.x * 4 + (tid >> 6);   // 512 blocks -> 2048 rows
  int lane = tid & 63;
  int t = row >> 6, b = row & 63;
  int tok = tokens[b * TLEN + t];
  float4 v = *reinterpret_cast<const float4*>(emb + (size_t)tok * EMBD + lane * 4);
  __hip_bfloat16* d = xb + (size_t)row * EMBD + lane * 4;
  d[0] = __float2bfloat16(v.x);
  d[1] = __float2bfloat16(v.y);
  d[2] = __float2bfloat16(v.z);
  d[3] = __float2bfloat16(v.w);
}

__device__ __forceinline__ void store_agent_u32(unsigned* p, unsigned v) {
  __hip_atomic_store(p, v, __ATOMIC_RELAXED, __HIP_MEMORY_SCOPE_AGENT);
}
__device__ __forceinline__ unsigned load_agent_u32(const unsigned* p) {
  return __hip_atomic_load(p, __ATOMIC_RELAXED, __HIP_MEMORY_SCOPE_AGENT);
}
__device__ __forceinline__ unsigned long long load_agent_u64(const void* p) {
  return __hip_atomic_load((const unsigned long long*)p, __ATOMIC_RELAXED,
                           __HIP_MEMORY_SCOPE_AGENT);
}
__device__ __forceinline__ void store_agent_f32(float* p, float v) {
  __hip_atomic_store(p, v, __ATOMIC_RELAXED, __HIP_MEMORY_SCOPE_AGENT);
}
__device__ __forceinline__ unsigned short bf16_bits(float x) {
  __hip_bfloat16 h = __float2bfloat16(x);
  unsigned short u;
  __builtin_memcpy(&u, &h, 2);
  return u;
}

// Half-grid barrier: syncs the 128 blocks of one rg only (A-reads are
// rg-local; the only cross-rg dep is stats, deferred to after the loop).
// Store-based, monotone values, two hops (arrive->leader poll->release).
__device__ __forceinline__ void half_barrier(unsigned* bar, int t, int cg,
                                             int rg, int xg, int tid, int lane) {
  __syncthreads();                        // all waves' stores drained
  const unsigned want = (unsigned)(t + 1);
  unsigned* hArr = bar + rg * 128;
  unsigned* hRel = bar + 256;
  if (cg == 0) {
    if (tid < 64) {                       // leader wave polls its 128 words
      if (lane == 0) store_agent_u32(hArr, want);
      for (;;) {
        unsigned long long a = load_agent_u64(hArr + 2 * lane);
        bool ok = ((unsigned)a >= want) && ((unsigned)(a >> 32) >= want);
        if (__all(ok)) break;
      }
      if (lane < 8) store_agent_u32(hRel + ((rg * 8 + lane) << 4), want);
    }
  } else {
    if (tid == 0) {
      store_agent_u32(hArr + cg, want);
      while (load_agent_u32(hRel + ((rg * 8 + xg) << 4)) < want)
        __builtin_amdgcn_s_sleep(1);
    }
  }
  __syncthreads();
}

// ---------------- persistent kernel: all 32 steps ----------------
// 256 blocks x 512 threads. cg=(j&7)|((j>>4)<<3) owns vocab cols cg*16..+15;
// rg=(j>>3)&1 owns batch rows rg*32..+31 (the cg-pair shares j%8 -> same XCD
// -> shared B panel in L2). 8 waves split K=2304. A/B depth-5 register rings.
// Per-step sync = rg-local half barrier. Bounds/stats reads happen ONCE after
// the t-loop (stats ring, one full barrier) -> t-loop is uniform across blocks.
__global__ __launch_bounds__(512, 1) void k_persist(
    const int* __restrict__ tokens,
    const __hip_bfloat16* __restrict__ WhT,   // [8192][2048]
    const __hip_bfloat16* __restrict__ WxT,   // [8192][256]
    const __hip_bfloat16* __restrict__ xb,    // [2048][256] row = t*64+b
    const float* __restrict__ bias,           // [8192]
    __hip_bfloat16* __restrict__ hring,       // [33][64][2048]
    float* __restrict__ stats,                // [31][3][64][128]
    float* __restrict__ out,                  // [64][32][64]
    unsigned* __restrict__ bar) {
  const int tid = threadIdx.x;
  const int lane = tid & 63;
  const int wid = tid >> 6;                  // 0..7 = K-split
  const int j = blockIdx.x;                  // physical id
  const int cg = (j & 7) | ((j >> 4) << 3);  // column group 0..127 (swizzled)
  const int rg = (j >> 3) & 1;               // row group 0..1
  const int xg = j & 7;                      // XCD-ish group for rel lines
  const int r0 = rg << 5;                    // first batch row

  __shared__ float racc[8][2][4][4][64];   // [wid][mf][gt][r][lane] 64KB
  __shared__ float sval[TLEN];

  const int rr = lane & 15;
  const int kg = lane >> 4;                 // 0..3 (K-subgroups of 8)

  // ---- loop-invariant base pointers ----
  const __hip_bfloat16* bBase[4];
#pragma unroll
  for (int gt = 0; gt < 4; ++gt)
    bBase[gt] = WhT + (size_t)((gt << 11) + (cg << 4) + rr) * VOCAB + wid * 256 + kg * 8;
  const __hip_bfloat16* bxBase[4];
#pragma unroll
  for (int gt = 0; gt < 4; ++gt)
    bxBase[gt] = WxT + (size_t)((gt << 11) + (cg << 4) + rr) * EMBD + wid * 32 + kg * 8;

  // ---- epilogue constants: this thread owns cell (rowg, v) ----
  const int m_e = wid >> 2;                 // 0..1
  const int r_e = wid & 3;                  // 0..3
  const int rowg = r0 + m_e * 16 + kg * 4 + r_e;   // global batch row
  const int v = (cg << 4) + rr;             // global vocab col
  float bias_r[4];
#pragma unroll
  for (int gt = 0; gt < 4; ++gt) bias_r[gt] = bias[gt * 2048 + v];
  float c_reg = 0.f;

  for (int t = 0; t < TLEN; ++t) {
    const __hip_bfloat16* hcur = hring + (size_t)t * (BATCH * VOCAB);
    __hip_bfloat16* hnext = (__hip_bfloat16*)hring + (size_t)(t + 1) * (BATCH * VOCAB);
    const int tok = (t < TLEN - 1) ? tokens[rowg * TLEN + t + 1] : 0;

    // ---- GEMM: z[32 rows x 64 zcols] over K=2304, 8 waves split K ----
    f32x4 acc[2][4];
#pragma unroll
    for (int mf = 0; mf < 2; ++mf)
#pragma unroll
      for (int gt = 0; gt < 4; ++gt) acc[mf][gt] = (f32x4){0.f, 0.f, 0.f, 0.f};

    const __hip_bfloat16* aBase = hcur + (size_t)(r0 + rr) * VOCAB + wid * 256 + kg * 8;
    const __hip_bfloat16* xBase = xb + (size_t)t * BATCH * EMBD +
                                  (size_t)(r0 + rr) * EMBD + wid * 32 + kg * 8;
    bf16x8 Ar[5][2];
    bf16x8 Br[5][4];
    auto issue = [&](int it) {
      int slot = it % 5;
      if (it < 8) {
        Ar[slot][0] = *(const bf16x8*)(aBase + it * 32);
        Ar[slot][1] = *(const bf16x8*)(aBase + 16 * VOCAB + it * 32);
#pragma unroll
        for (int gt = 0; gt < 4; ++gt)
          Br[slot][gt] = *(const bf16x8*)(bBase[gt] + it * 32);
      } else {
        Ar[slot][0] = *(const bf16x8*)(xBase);
        Ar[slot][1] = *(const bf16x8*)(xBase + 16 * EMBD);
#pragma unroll
        for (int gt = 0; gt < 4; ++gt)
          Br[slot][gt] = *(const bf16x8*)(bxBase[gt]);
      }
    };

#pragma unroll
    for (int it = 0; it < 5; ++it) issue(it);
#pragma unroll
    for (int it = 0; it < 9; ++it) {
      const int sl = it % 5;
#pragma unroll
      for (int gt = 0; gt < 4; ++gt) {
        acc[0][gt] = __builtin_amdgcn_mfma_f32_16x16x32_bf16(Ar[sl][0], Br[sl][gt], acc[0][gt], 0, 0, 0);
        acc[1][gt] = __builtin_amdgcn_mfma_f32_16x16x32_bf16(Ar[sl][1], Br[sl][gt], acc[1][gt], 0, 0, 0);
      }
      if (it + 5 < 9) issue(it + 5);
    }

    // ---- cross-wave K reduction ----
#pragma unroll
    for (int mf = 0; mf < 2; ++mf)
#pragma unroll
      for (int gt = 0; gt < 4; ++gt)
#pragma unroll
        for (int r = 0; r < 4; ++r) racc[wid][mf][gt][r][lane] = acc[mf][gt][r];
    __syncthreads();

    // ---- epilogue: one cell per thread; all 4 gates from LDS ----
    float z[4];
#pragma unroll
    for (int gt = 0; gt < 4; ++gt) {
      float s = bias_r[gt];
#pragma unroll
      for (int w = 0; w < 8; ++w) s += racc[w][m_e][gt][r_e][lane];
      z[gt] = s;
    }
    float gi = 1.f / (1.f + __expf(-z[0]));
    float gf = 1.f / (1.f + __expf(-z[1]));
    float go = 1.f / (1.f + __expf(-z[3]));
    float cnew = gf * c_reg + gi * tanhf(z[2]);
    float hn = go * tanhf(cnew);
    c_reg = cnew;

    if (t < TLEN - 1) {
      // h store: pack col pairs -> one u32 agent store (LLC) per even lane
      unsigned b0 = bf16_bits(hn);
      unsigned q0 = (unsigned)__shfl_xor((int)b0, 1);
      if (!(rr & 1))
        store_agent_u32((unsigned*)(hnext + rowg * VOCAB + v), b0 | (q0 << 16));

      // stats partials over this block's 16 cols -> slot t (consumed post-loop)
      float e = __expf(hn);
      float sl = (v < tok) ? e : 0.f;
      float st = (v == tok) ? e : 0.f;
#pragma unroll
      for (int mm = 1; mm <= 8; mm <<= 1) {
        e += __shfl_xor(e, mm);
        sl += __shfl_xor(sl, mm);
        st += __shfl_xor(st, mm);
      }
      if (rr == 0) {
        float* stn = stats + (size_t)t * 3 * BATCH * NCG;
        store_agent_f32(&stn[(0 * BATCH + rowg) * NCG + cg], e);
        store_agent_f32(&stn[(1 * BATCH + rowg) * NCG + cg], sl);
        store_agent_f32(&stn[(2 * BATCH + rowg) * NCG + cg], st);
      }

      half_barrier(bar, t, cg, rg, xg, tid, lane);
    }
  }

  // ---- one FULL barrier (stats of all rg visible), then bounds + out ----
  {
    __syncthreads();
    unsigned* fArr = bar + 512;
    unsigned* fRel = bar + 768;
    if (j == 0) {
      if (tid < 64) {
        if (lane == 0) store_agent_u32(fArr, 1u);
        for (;;) {
          unsigned long long a = load_agent_u64(fArr + 2 * lane);
          unsigned long long b = load_agent_u64(fArr + 128 + 2 * lane);
          bool ok = ((unsigned)a >= 1u) && ((unsigned)(a >> 32) >= 1u) &&
                    ((unsigned)b >= 1u) && ((unsigned)(b >> 32) >= 1u);
          if (__all(ok)) break;
        }
        if (lane < 8) store_agent_u32(fRel + (lane << 4), 1u);
      }
    } else {
      if (tid == 0) {
        store_agent_u32(fArr + j, 1u);
        if (j < BATCH)                      // only bounds blocks must wait
          while (load_agent_u32(fRel + ((j & 7) << 4)) < 1u)
            __builtin_amdgcn_s_sleep(1);
      }
    }
    __syncthreads();
  }

  if (j < BATCH) {
    // sval[t]: wave w handles t = w, w+8, w+16, w+24
    for (int tt = wid; tt < TLEN; tt += 8) {
      float val;
      if (tt == 0) {
        int tk = tokens[j * TLEN];
        val = 1.5f * (2.f * tk + 1.f) * (1.f / 2048.f);
      } else {
        const float* st = stats + (size_t)(tt - 1) * 3 * BATCH * NCG;
        float2 u0 = *reinterpret_cast<const float2*>(st + (0 * BATCH + j) * NCG + lane * 2);
        float2 u1 = *reinterpret_cast<const float2*>(st + (1 * BATCH + j) * NCG + lane * 2);
        float2 u2 = *reinterpret_cast<const float2*>(st + (2 * BATCH + j) * NCG + lane * 2);
        float a0 = u0.x + u0.y, a1 = u1.x + u1.y, a2 = u2.x + u2.y;
#pragma unroll
        for (int mm = 1; mm <= 32; mm <<= 1) {
          a0 += __shfl_xor(a0, mm);
          a1 += __shfl_xor(a1, mm);
          a2 += __shfl_xor(a2, mm);
        }
        val = 1.5f * (2.f * a1 + a2) / a0;
      }
      if (lane == 0) sval[tt] = val;
    }
    __syncthreads();
    for (int idx = tid; idx < TLEN * LATD; idx += 512) {
      int tp = idx >> 6, d = idx & 63;
      out[j * TLEN * LATD + idx] = (d < TLEN && d <= tp) ? sval[d] : 1.5f;
    }
  }
}

extern "C" void kernel_launch(void* const* d_in, const int* in_sizes, int n_in,
                              void* d_out, int out_size, void* d_ws, size_t ws_size,
                              hipStream_t stream) {
  (void)in_sizes; (void)n_in; (void)out_size; (void)ws_size;
  const int* tokens = (const int*)d_in[0];
  const float* emb  = (const float*)d_in[1];
  const float* Wx   = (const float*)d_in[2];
  const float* Wh   = (const float*)d_in[3];
  const float* bias = (const float*)d_in[4];
  float* out = (float*)d_out;
  char* ws = (char*)d_ws;

  __hip_bfloat16* WhT = (__hip_bfloat16*)(ws);               // 33,554,432 B
  __hip_bfloat16* WxT = (__hip_bfloat16*)(ws + 33554432);    //  4,194,304 B
  __hip_bfloat16* xb  = (__hip_bfloat16*)(ws + 37748736);    //  1,048,576 B
  __hip_bfloat16* hr  = (__hip_bfloat16*)(ws + 38797312);    //  8,650,752 B (33 slots)
  float* stats        = (float*)(ws + 47448064);             //  3,047,424 B (31 slots)
  unsigned* bar       = (unsigned*)(ws + 50495488);          //      3,584 B

  k_init<<<512, 256, 0, stream>>>((ushort*)hr, bar);
  k_transpose<<<4096, 256, 0, stream>>>(Wh, WhT, 2048);
  k_transpose<<<512, 256, 0, stream>>>(Wx, WxT, 256);
  k_gather<<<512, 256, 0, stream>>>(tokens, emb, xb);
  k_persist<<<NBLK, 512, 0, stream>>>(tokens, WhT, WxT, xb, bias, hr, stats, out, bar);
}